// Round 11
// baseline (85.472 us; speedup 1.0000x reference)
//
#include <hip/hip_runtime.h>
#include <math.h>

#define V 50257
#define E 1024
#define HH 1024
#define LL 256

// d_out layout (floats): y | h_new(2*H) | c_new(2*H) | h_t_tilde(H) | a_t(L) | p_t
#define O_H  (V)
#define O_C  (V + 2*HH)
#define O_HT (V + 4*HH)
#define O_A  (V + 5*HH)
#define O_P  (V + 5*HH + LL)

// workspace layout (floats)
#define W_T    0       // tanh(Wp@h2)            [1024]
#define W_V    1024    // h2 @ Wbil              [1024] (atomics; zeroed by k_lstmA)
#define W_H1   2048    // aligned h1 copy; reused as aligned h_t_tilde copy [1024]
#define W_H2   3072    // aligned h2 copy        [1024]
#define W_Z    4096    // logits                 [50257]
#define W_BS   54400   // per-block expsum       [2048]
// LSTM1 gate partials (4 per u = 4096 floats) stashed in out[0..4096) -- y region,
// overwritten by k_sub at the end of every call.

#define NBL   2048     // k_logits blocks (256 thr, 4 waves each)
// rows per block: 24 + (b < 50257 - 2048*24 = 1105)

__device__ __forceinline__ float sigmoidf_(float x) { return 1.f / (1.f + expf(-x)); }
__device__ __forceinline__ float dot4(float4 a, float4 b) {
    return a.x * b.x + a.y * b.y + a.z * b.z + a.w * b.w;
}

__device__ __forceinline__ float block_sum(float v, float* red) {
    int lane = threadIdx.x & 63, wv = threadIdx.x >> 6;
#pragma unroll
    for (int o = 32; o > 0; o >>= 1) v += __shfl_down(v, o, 64);
    __syncthreads();                 // protect red[] reuse across calls
    if (lane == 0) red[wv] = v;
    __syncthreads();
    return red[0] + red[1] + red[2] + red[3];
}

// ---- stage A (512 thr): LSTM0 full cell + Whh1@h0[1] gate partials ----
__global__ __launch_bounds__(512) void k_lstmA(
    const float* __restrict__ Wih0, const float* __restrict__ Whh0,
    const float* __restrict__ Whh1,
    const float* __restrict__ bih0, const float* __restrict__ bhh0,
    const float* __restrict__ emb, const int* __restrict__ tok,
    const float* __restrict__ htt,
    const float* __restrict__ h0, const float* __restrict__ c0,
    float* __restrict__ h1o, float* __restrict__ c1o, float* __restrict__ h1w,
    float* __restrict__ p1, float* __restrict__ vzero) {
    const int u = blockIdx.x, tid = threadIdx.x;
    if (tid == 0) vzero[u] = 0.f;     // zero W_V for k_ptv atomics
    const float4* xa4 = (const float4*)(emb + (size_t)tok[0] * E);
    const float4* xb4 = (const float4*)htt;
    const float4* r0 = (const float4*)(Wih0 + (size_t)u * 2048);
    const float4* r1 = (const float4*)(Wih0 + (size_t)(u + HH) * 2048);
    const float4* r2 = (const float4*)(Wih0 + (size_t)(u + 2*HH) * 2048);
    const float4* r3 = (const float4*)(Wih0 + (size_t)(u + 3*HH) * 2048);
    float4 xv = (tid < 256) ? xa4[tid] : xb4[tid - 256];
    float a0 = dot4(r0[tid], xv), a1 = dot4(r1[tid], xv);
    float a2 = dot4(r2[tid], xv), a3 = dot4(r3[tid], xv);
    float b0 = 0.f, b1 = 0.f, b2 = 0.f, b3 = 0.f;
    if (tid < 256) {                  // wave-uniform branch (waves 0-3)
        const float4* s0 = (const float4*)(Whh0 + (size_t)u * HH);
        const float4* s1 = (const float4*)(Whh0 + (size_t)(u + HH) * HH);
        const float4* s2 = (const float4*)(Whh0 + (size_t)(u + 2*HH) * HH);
        const float4* s3 = (const float4*)(Whh0 + (size_t)(u + 3*HH) * HH);
        float4 hv = ((const float4*)h0)[tid];
        a0 += dot4(s0[tid], hv); a1 += dot4(s1[tid], hv);
        a2 += dot4(s2[tid], hv); a3 += dot4(s3[tid], hv);
    } else {                          // waves 4-7
        int j = tid - 256;
        const float4* t0 = (const float4*)(Whh1 + (size_t)u * HH);
        const float4* t1 = (const float4*)(Whh1 + (size_t)(u + HH) * HH);
        const float4* t2 = (const float4*)(Whh1 + (size_t)(u + 2*HH) * HH);
        const float4* t3 = (const float4*)(Whh1 + (size_t)(u + 3*HH) * HH);
        float4 gv = ((const float4*)(h0 + HH))[j];
        b0 = dot4(t0[j], gv); b1 = dot4(t1[j], gv);
        b2 = dot4(t2[j], gv); b3 = dot4(t3[j], gv);
    }
    const int lane = tid & 63, wv = tid >> 6;
#pragma unroll
    for (int o = 32; o > 0; o >>= 1) {
        a0 += __shfl_down(a0, o, 64); a1 += __shfl_down(a1, o, 64);
        a2 += __shfl_down(a2, o, 64); a3 += __shfl_down(a3, o, 64);
        b0 += __shfl_down(b0, o, 64); b1 += __shfl_down(b1, o, 64);
        b2 += __shfl_down(b2, o, 64); b3 += __shfl_down(b3, o, 64);
    }
    __shared__ float sma[8][4], smb[8][4];
    if (lane == 0) {
        sma[wv][0] = a0; sma[wv][1] = a1; sma[wv][2] = a2; sma[wv][3] = a3;
        smb[wv][0] = b0; smb[wv][1] = b1; smb[wv][2] = b2; smb[wv][3] = b3;
    }
    __syncthreads();
    if (tid == 0) {
        float g[4], p[4];
#pragma unroll
        for (int i = 0; i < 4; ++i) {
            float ga = 0.f, pb = 0.f;
#pragma unroll
            for (int w = 0; w < 8; ++w) { ga += sma[w][i]; pb += smb[w][i]; }
            g[i] = ga + bih0[u + i*HH] + bhh0[u + i*HH];
            p[i] = pb;
        }
        float c = sigmoidf_(g[1]) * c0[u] + sigmoidf_(g[0]) * tanhf(g[2]);
        float h = sigmoidf_(g[3]) * tanhf(c);
        h1o[u] = h; c1o[u] = c; h1w[u] = h;
        p1[u*4+0] = p[0]; p1[u*4+1] = p[1]; p1[u*4+2] = p[2]; p1[u*4+3] = p[3];
    }
}

// ---- stage B (256 thr): LSTM1 = Wih1@h1 + stashed Whh1 partials ----
__global__ void k_lstmB(
    const float* __restrict__ Wih1,
    const float* __restrict__ bih1, const float* __restrict__ bhh1,
    const float* __restrict__ h1w, const float* __restrict__ p1,
    const float* __restrict__ h0, const float* __restrict__ c0,
    float* __restrict__ h2o, float* __restrict__ c2o, float* __restrict__ h2w) {
    const int u = blockIdx.x, tid = threadIdx.x;
    const float4* r0 = (const float4*)(Wih1 + (size_t)u * HH);
    const float4* r1 = (const float4*)(Wih1 + (size_t)(u + HH) * HH);
    const float4* r2 = (const float4*)(Wih1 + (size_t)(u + 2*HH) * HH);
    const float4* r3 = (const float4*)(Wih1 + (size_t)(u + 3*HH) * HH);
    float4 hv = ((const float4*)h1w)[tid];
    float a0 = dot4(r0[tid], hv), a1 = dot4(r1[tid], hv);
    float a2 = dot4(r2[tid], hv), a3 = dot4(r3[tid], hv);
    const int lane = tid & 63, wv = tid >> 6;
#pragma unroll
    for (int o = 32; o > 0; o >>= 1) {
        a0 += __shfl_down(a0, o, 64); a1 += __shfl_down(a1, o, 64);
        a2 += __shfl_down(a2, o, 64); a3 += __shfl_down(a3, o, 64);
    }
    __shared__ float sm[4][4];
    if (lane == 0) { sm[wv][0] = a0; sm[wv][1] = a1; sm[wv][2] = a2; sm[wv][3] = a3; }
    __syncthreads();
    if (tid == 0) {
        float g[4];
#pragma unroll
        for (int i = 0; i < 4; ++i)
            g[i] = sm[0][i] + sm[1][i] + sm[2][i] + sm[3][i]
                 + p1[u*4+i] + bih1[u + i*HH] + bhh1[u + i*HH];
        float c = sigmoidf_(g[1]) * c0[HH + u] + sigmoidf_(g[0]) * tanhf(g[2]);
        float h = sigmoidf_(g[3]) * tanhf(c);
        h2o[u] = h; c2o[u] = c; h2w[u] = h;
    }
}

// ---- blocks [0,1024): t = tanh(Wp @ h2);  blocks [1024,1056): v += h2 @ Wbil tile ----
__global__ void k_ptv(const float* __restrict__ Wp, const float* __restrict__ Wbil,
                      const float* __restrict__ h2, float* __restrict__ t_out,
                      float* __restrict__ v_out) {
    __shared__ float red[4];
    if (blockIdx.x < HH) {
        int r = blockIdx.x;
        const float4* row = (const float4*)(Wp + (size_t)r * HH);
        const float4* h24 = (const float4*)h2;
        float acc = dot4(row[threadIdx.x], h24[threadIdx.x]);
        float tot = block_sum(acc, red);
        if (threadIdx.x == 0) t_out[r] = tanhf(tot);
    } else {
        int b = blockIdx.x - HH;        // 0..31, h-chunk of 32 rows
        int h0 = b * 32;
        int k4 = threadIdx.x;           // float4 column slot
        const float4* W4 = (const float4*)Wbil;
        float4 acc = make_float4(0.f, 0.f, 0.f, 0.f);
        for (int h = h0; h < h0 + 32; ++h) {
            float hv = h2[h];
            float4 w = W4[(size_t)h * 256 + k4];
            acc.x += hv * w.x; acc.y += hv * w.y;
            acc.z += hv * w.z; acc.w += hv * w.w;
        }
        atomicAdd(&v_out[k4 * 4 + 0], acc.x);
        atomicAdd(&v_out[k4 * 4 + 1], acc.y);
        atomicAdd(&v_out[k4 * 4 + 2], acc.z);
        atomicAdd(&v_out[k4 * 4 + 3], acc.w);
    }
}

// ---- comb with fully-absorbed attention (unchanged) ----
__global__ void k_combattn(const float* __restrict__ wdot, const float* __restrict__ t,
                           const float* __restrict__ v, const float* __restrict__ hs,
                           const float* __restrict__ h2, const float* __restrict__ Wcomb,
                           const float* __restrict__ bcomb,
                           float* __restrict__ outv, float* __restrict__ outv2,
                           float* __restrict__ ato, float* __restrict__ pto) {
    const int u = blockIdx.x, tid = threadIdx.x;
    const int lane = tid & 63, wv = tid >> 6;
    __shared__ float red[4];
    __shared__ float ssc[32];
    __shared__ float sa[LL];
    float p;
    {
        const float4* w4 = (const float4*)wdot;
        const float4* t4 = (const float4*)t;
        float acc = dot4(w4[tid], t4[tid]);
        p = (float)LL * sigmoidf_(block_sum(acc, red));
    }
    if (u == 0 && tid == 0) pto[0] = p;
    const int si = (int)rintf(p);
    const int lo = max(si - 10, 0), hi = min(si + 10, LL - 1);
    const int W = hi - lo + 1;            // <= 21
    const float4* v4 = (const float4*)v;
    for (int l = lo + wv; l <= hi; l += 4) {
        const float4* row = (const float4*)(hs + (size_t)l * HH);
        float a = 0.f;
#pragma unroll
        for (int j = lane; j < 256; j += 64) a += dot4(row[j], v4[j]);
#pragma unroll
        for (int o = 32; o > 0; o >>= 1) a += __shfl_xor(a, o, 64);
        if (lane == 0) ssc[l - lo] = a;
    }
    __syncthreads();
    float M = -INFINITY;
    for (int i = 0; i < W; ++i) M = fmaxf(M, ssc[i]);
    float S = 0.f;
    for (int i = 0; i < W; ++i) S += expf(ssc[i] - M);
    {
        bool mask = (tid >= lo) && (tid <= hi);
        int wi = min(max(tid - lo, 0), 31);
        float e = mask ? expf(ssc[wi] - M) : 0.f;
        float d = (float)tid - p;
        float at = mask ? (e / S) * expf(d * d * 0.04f) : 0.f;  // exp(+d^2/(D/2)^2), faithful
        sa[tid] = at;
        if (u == 0) ato[tid] = at;
    }
    __syncthreads();
    const float4* hs4 = (const float4*)hs;
    float4 c = make_float4(0.f, 0.f, 0.f, 0.f);
    for (int l = lo; l <= hi; ++l) {
        float a = sa[l];
        float4 hv = hs4[(size_t)l * 256 + tid];
        c.x += a * hv.x; c.y += a * hv.y; c.z += a * hv.z; c.w += a * hv.w;
    }
    const float inv_win = 1.f / (float)W;
    c.x *= inv_win; c.y *= inv_win; c.z *= inv_win; c.w *= inv_win;
    {
        const float4* row = (const float4*)(Wcomb + (size_t)u * (2 * HH));
        const float4* h24 = (const float4*)h2;
        float acc = dot4(row[tid], c) + dot4(row[256 + tid], h24[tid]);
        float tot = block_sum(acc, red);
        if (tid == 0) {
            float h = tanhf(tot + bcomb[u]);
            outv[u] = h; outv2[u] = h;
        }
    }
}

// ---- logits: 2048 blocks x 256 thr; contiguous 24/25-row block partition;
//      wave-stride-4 rows; rolled depth-2 row pipeline; max-free exp-sum ----
__global__ void k_logits(const float* __restrict__ Wout, const float* __restrict__ bout,
                         const float* __restrict__ x, float* __restrict__ z,
                         float* __restrict__ bsum) {
    const int b = blockIdx.x, tid = threadIdx.x;
    const int lane = tid & 63, wvi = tid >> 6;
    const int start = b * 24 + min(b, 1105);
    const int cnt = 24 + (b < 1105 ? 1 : 0);
    const int rend = start + cnt;
    const float4* x4 = (const float4*)x;
    float4 x0 = x4[lane], x1 = x4[lane + 64], x2 = x4[lane + 128], x3 = x4[lane + 192];
    float s = 0.f;
    int r = start + wvi;                  // wave-uniform
    float4 c0, c1, c2, c3;
    bool has = r < rend;
    if (has) {
        const float4* rp = (const float4*)(Wout + (size_t)r * 1024) + lane;
        c0 = rp[0]; c1 = rp[64]; c2 = rp[128]; c3 = rp[192];
    }
    while (has) {
        const int rn = r + 4;
        const bool hasn = rn < rend;
        float4 n0, n1, n2, n3;
        if (hasn) {                       // issue next row's loads before reducing current
            const float4* np = (const float4*)(Wout + (size_t)rn * 1024) + lane;
            n0 = np[0]; n1 = np[64]; n2 = np[128]; n3 = np[192];
        }
        float acc = dot4(c0, x0) + dot4(c1, x1) + dot4(c2, x2) + dot4(c3, x3);
#pragma unroll
        for (int o = 32; o > 0; o >>= 1) acc += __shfl_xor(acc, o, 64);
        float zz = acc + bout[r];
        if (lane == 0) z[r] = zz;
        s += expf(zz);                    // tanh-bounded x -> |z| small, no overflow
        r = rn; has = hasn;
        c0 = n0; c1 = n1; c2 = n2; c3 = n3;
    }
    __shared__ float wsv[4];
    if (lane == 0) wsv[wvi] = s;
    __syncthreads();
    if (tid == 0) bsum[b] = wsv[0] + wsv[1] + wsv[2] + wsv[3];
}

// ---- fused: sum 2048 block expsums -> logZ; y = z - logZ ----
__global__ void k_sub(const float* __restrict__ z, const float* __restrict__ bsum,
                      float* __restrict__ y) {
    const int tid = threadIdx.x;
    __shared__ float red[4];
    __shared__ float lzs;
    float s = 0.f;
    for (int i = tid; i < NBL; i += 256) s += bsum[i];
    float S = block_sum(s, red);
    if (tid == 0) lzs = logf(S);
    __syncthreads();
    const float lz = lzs;
    int i = blockIdx.x * 256 + tid;
    if (i < V) y[i] = z[i] - lz;
}

extern "C" void kernel_launch(void* const* d_in, const int* in_sizes, int n_in,
                              void* d_out, int out_size, void* d_ws, size_t ws_size,
                              hipStream_t stream) {
    const int*   tok   = (const int*)  d_in[0];
    const float* h0    = (const float*)d_in[1];
    const float* c0    = (const float*)d_in[2];
    const float* hs    = (const float*)d_in[3];
    const float* htt   = (const float*)d_in[4];
    const float* emb   = (const float*)d_in[5];
    const float* Wp    = (const float*)d_in[6];
    const float* wdot  = (const float*)d_in[7];
    const float* Wbil  = (const float*)d_in[8];
    const float* Wcomb = (const float*)d_in[9];
    const float* bcomb = (const float*)d_in[10];
    const float* Wih0  = (const float*)d_in[11];
    const float* Whh0  = (const float*)d_in[12];
    const float* bih0  = (const float*)d_in[13];
    const float* bhh0  = (const float*)d_in[14];
    const float* Wih1  = (const float*)d_in[15];
    const float* Whh1  = (const float*)d_in[16];
    const float* bih1  = (const float*)d_in[17];
    const float* bhh1  = (const float*)d_in[18];
    const float* Wout  = (const float*)d_in[19];
    const float* bout  = (const float*)d_in[20];

    float* out = (float*)d_out;
    float* ws  = (float*)d_ws;

    float* h1o  = out + O_H;
    float* h2o  = out + O_H + HH;
    float* c1o  = out + O_C;
    float* c2o  = out + O_C + HH;
    float* htto = out + O_HT;
    float* ato  = out + O_A;
    float* pto  = out + O_P;
    float* p1   = out;            // y[0..4096) as scratch; overwritten by k_sub

    hipLaunchKernelGGL(k_lstmA, dim3(1024), dim3(512), 0, stream,
                       Wih0, Whh0, Whh1, bih0, bhh0, emb, tok, htt, h0, c0,
                       h1o, c1o, ws + W_H1, p1, ws + W_V);
    hipLaunchKernelGGL(k_lstmB, dim3(1024), dim3(256), 0, stream,
                       Wih1, bih1, bhh1, ws + W_H1, p1, h0, c0,
                       h2o, c2o, ws + W_H2);
    hipLaunchKernelGGL(k_ptv, dim3(1024 + 32), dim3(256), 0, stream,
                       Wp, Wbil, ws + W_H2, ws + W_T, ws + W_V);
    hipLaunchKernelGGL(k_combattn, dim3(1024), dim3(256), 0, stream,
                       wdot, ws + W_T, ws + W_V, hs, ws + W_H2, Wcomb, bcomb,
                       htto, ws + W_H1, ato, pto);   // W_H1 reused as aligned x copy
    hipLaunchKernelGGL(k_logits, dim3(NBL), dim3(256), 0, stream,
                       Wout, bout, ws + W_H1, ws + W_Z, ws + W_BS);
    hipLaunchKernelGGL(k_sub, dim3((V + 255) / 256), dim3(256), 0, stream,
                       ws + W_Z, ws + W_BS, out);
}

// Round 13
// 82.716 us; speedup vs baseline: 1.0333x; 1.0333x over previous
//
#include <hip/hip_runtime.h>
#include <math.h>

#define V 50257
#define E 1024
#define HH 1024
#define LL 256

// d_out layout (floats): y | h_new(2*H) | c_new(2*H) | h_t_tilde(H) | a_t(L) | p_t
#define O_H  (V)
#define O_C  (V + 2*HH)
#define O_HT (V + 4*HH)
#define O_A  (V + 5*HH)
#define O_P  (V + 5*HH + LL)

// workspace layout (floats)
#define W_T    0       // tanh(Wp@h2)            [1024]
#define W_V    1024    // h2 @ Wbil              [1024] (atomics; zeroed by k_lstmA)
#define W_H1   2048    // aligned h1 copy; reused as aligned h_t_tilde copy [1024]
#define W_H2   3072    // aligned h2 copy        [1024]
#define W_Z    4096    // logits                 [50257]
#define W_BS   54400   // per-block expsum       [1024]
// LSTM1 gate partials (4 per u = 4096 floats) stashed in out[0..4096) -- y region,
// overwritten by k_sub at the end of every call.

#define NWL   8192     // waves in k_logits (1024 blocks * 8)
#define MAXR  7        // ceil(V / NWL)

__device__ __forceinline__ float sigmoidf_(float x) { return 1.f / (1.f + expf(-x)); }
__device__ __forceinline__ float dot4(float4 a, float4 b) {
    return a.x * b.x + a.y * b.y + a.z * b.z + a.w * b.w;
}

__device__ __forceinline__ float block_sum(float v, float* red) {
    int lane = threadIdx.x & 63, wv = threadIdx.x >> 6;
#pragma unroll
    for (int o = 32; o > 0; o >>= 1) v += __shfl_down(v, o, 64);
    __syncthreads();                 // protect red[] reuse across calls
    if (lane == 0) red[wv] = v;
    __syncthreads();
    return red[0] + red[1] + red[2] + red[3];
}

// ---- stage A (512 thr): LSTM0 full cell + Whh1@h0[1] gate partials ----
__global__ __launch_bounds__(512) void k_lstmA(
    const float* __restrict__ Wih0, const float* __restrict__ Whh0,
    const float* __restrict__ Whh1,
    const float* __restrict__ bih0, const float* __restrict__ bhh0,
    const float* __restrict__ emb, const int* __restrict__ tok,
    const float* __restrict__ htt,
    const float* __restrict__ h0, const float* __restrict__ c0,
    float* __restrict__ h1o, float* __restrict__ c1o, float* __restrict__ h1w,
    float* __restrict__ p1, float* __restrict__ vzero) {
    const int u = blockIdx.x, tid = threadIdx.x;
    if (tid == 0) vzero[u] = 0.f;     // zero W_V for k_ptv atomics
    const float4* xa4 = (const float4*)(emb + (size_t)tok[0] * E);
    const float4* xb4 = (const float4*)htt;
    const float4* r0 = (const float4*)(Wih0 + (size_t)u * 2048);
    const float4* r1 = (const float4*)(Wih0 + (size_t)(u + HH) * 2048);
    const float4* r2 = (const float4*)(Wih0 + (size_t)(u + 2*HH) * 2048);
    const float4* r3 = (const float4*)(Wih0 + (size_t)(u + 3*HH) * 2048);
    float4 xv = (tid < 256) ? xa4[tid] : xb4[tid - 256];
    float a0 = dot4(r0[tid], xv), a1 = dot4(r1[tid], xv);
    float a2 = dot4(r2[tid], xv), a3 = dot4(r3[tid], xv);
    float b0 = 0.f, b1 = 0.f, b2 = 0.f, b3 = 0.f;
    if (tid < 256) {                  // wave-uniform branch (waves 0-3)
        const float4* s0 = (const float4*)(Whh0 + (size_t)u * HH);
        const float4* s1 = (const float4*)(Whh0 + (size_t)(u + HH) * HH);
        const float4* s2 = (const float4*)(Whh0 + (size_t)(u + 2*HH) * HH);
        const float4* s3 = (const float4*)(Whh0 + (size_t)(u + 3*HH) * HH);
        float4 hv = ((const float4*)h0)[tid];
        a0 += dot4(s0[tid], hv); a1 += dot4(s1[tid], hv);
        a2 += dot4(s2[tid], hv); a3 += dot4(s3[tid], hv);
    } else {                          // waves 4-7
        int j = tid - 256;
        const float4* t0 = (const float4*)(Whh1 + (size_t)u * HH);
        const float4* t1 = (const float4*)(Whh1 + (size_t)(u + HH) * HH);
        const float4* t2 = (const float4*)(Whh1 + (size_t)(u + 2*HH) * HH);
        const float4* t3 = (const float4*)(Whh1 + (size_t)(u + 3*HH) * HH);
        float4 gv = ((const float4*)(h0 + HH))[j];
        b0 = dot4(t0[j], gv); b1 = dot4(t1[j], gv);
        b2 = dot4(t2[j], gv); b3 = dot4(t3[j], gv);
    }
    const int lane = tid & 63, wv = tid >> 6;
#pragma unroll
    for (int o = 32; o > 0; o >>= 1) {
        a0 += __shfl_down(a0, o, 64); a1 += __shfl_down(a1, o, 64);
        a2 += __shfl_down(a2, o, 64); a3 += __shfl_down(a3, o, 64);
        b0 += __shfl_down(b0, o, 64); b1 += __shfl_down(b1, o, 64);
        b2 += __shfl_down(b2, o, 64); b3 += __shfl_down(b3, o, 64);
    }
    __shared__ float sma[8][4], smb[8][4];
    if (lane == 0) {
        sma[wv][0] = a0; sma[wv][1] = a1; sma[wv][2] = a2; sma[wv][3] = a3;
        smb[wv][0] = b0; smb[wv][1] = b1; smb[wv][2] = b2; smb[wv][3] = b3;
    }
    __syncthreads();
    if (tid == 0) {
        float g[4], p[4];
#pragma unroll
        for (int i = 0; i < 4; ++i) {
            float ga = 0.f, pb = 0.f;
#pragma unroll
            for (int w = 0; w < 8; ++w) { ga += sma[w][i]; pb += smb[w][i]; }
            g[i] = ga + bih0[u + i*HH] + bhh0[u + i*HH];
            p[i] = pb;
        }
        float c = sigmoidf_(g[1]) * c0[u] + sigmoidf_(g[0]) * tanhf(g[2]);
        float h = sigmoidf_(g[3]) * tanhf(c);
        h1o[u] = h; c1o[u] = c; h1w[u] = h;
        p1[u*4+0] = p[0]; p1[u*4+1] = p[1]; p1[u*4+2] = p[2]; p1[u*4+3] = p[3];
    }
}

// ---- stage B (512 thr): LSTM1 = Wih1@h1 + stashed Whh1 partials ----
// threads 0-255 handle gate rows u, u+H; threads 256-511 handle u+2H, u+3H.
__global__ __launch_bounds__(512) void k_lstmB(
    const float* __restrict__ Wih1,
    const float* __restrict__ bih1, const float* __restrict__ bhh1,
    const float* __restrict__ h1w, const float* __restrict__ p1,
    const float* __restrict__ h0, const float* __restrict__ c0,
    float* __restrict__ h2o, float* __restrict__ c2o, float* __restrict__ h2w) {
    const int u = blockIdx.x, tid = threadIdx.x;
    const int j = tid & 255, half = tid >> 8;
    const int ra = u + (2 * half) * HH;
    const float4* pa = (const float4*)(Wih1 + (size_t)ra * HH);
    const float4* pb = (const float4*)(Wih1 + (size_t)(ra + HH) * HH);
    float4 hv = ((const float4*)h1w)[j];
    float a = dot4(pa[j], hv), b = dot4(pb[j], hv);
    const int lane = tid & 63, wv = tid >> 6;   // wv 0..7 (0-3 = half 0, 4-7 = half 1)
#pragma unroll
    for (int o = 32; o > 0; o >>= 1) {
        a += __shfl_down(a, o, 64); b += __shfl_down(b, o, 64);
    }
    __shared__ float sm[8][2];
    if (lane == 0) { sm[wv][0] = a; sm[wv][1] = b; }
    __syncthreads();
    if (tid == 0) {
        float g[4];
        g[0] = sm[0][0] + sm[1][0] + sm[2][0] + sm[3][0];
        g[1] = sm[0][1] + sm[1][1] + sm[2][1] + sm[3][1];
        g[2] = sm[4][0] + sm[5][0] + sm[6][0] + sm[7][0];
        g[3] = sm[4][1] + sm[5][1] + sm[6][1] + sm[7][1];
#pragma unroll
        for (int i = 0; i < 4; ++i)
            g[i] += p1[u*4+i] + bih1[u + i*HH] + bhh1[u + i*HH];
        float c = sigmoidf_(g[1]) * c0[HH + u] + sigmoidf_(g[0]) * tanhf(g[2]);
        float h = sigmoidf_(g[3]) * tanhf(c);
        h2o[u] = h; c2o[u] = c; h2w[u] = h;
    }
}

// ---- blocks [0,1024): t = tanh(Wp @ h2);  blocks [1024,1056): v += h2 @ Wbil tile ----
__global__ void k_ptv(const float* __restrict__ Wp, const float* __restrict__ Wbil,
                      const float* __restrict__ h2, float* __restrict__ t_out,
                      float* __restrict__ v_out) {
    __shared__ float red[4];
    if (blockIdx.x < HH) {
        int r = blockIdx.x;
        const float4* row = (const float4*)(Wp + (size_t)r * HH);
        const float4* h24 = (const float4*)h2;
        float acc = dot4(row[threadIdx.x], h24[threadIdx.x]);
        float tot = block_sum(acc, red);
        if (threadIdx.x == 0) t_out[r] = tanhf(tot);
    } else {
        int b = blockIdx.x - HH;        // 0..31, h-chunk of 32 rows
        int h0 = b * 32;
        int k4 = threadIdx.x;           // float4 column slot
        const float4* W4 = (const float4*)Wbil;
        float4 acc = make_float4(0.f, 0.f, 0.f, 0.f);
        for (int h = h0; h < h0 + 32; ++h) {
            float hv = h2[h];
            float4 w = W4[(size_t)h * 256 + k4];
            acc.x += hv * w.x; acc.y += hv * w.y;
            acc.z += hv * w.z; acc.w += hv * w.w;
        }
        atomicAdd(&v_out[k4 * 4 + 0], acc.x);
        atomicAdd(&v_out[k4 * 4 + 1], acc.y);
        atomicAdd(&v_out[k4 * 4 + 2], acc.z);
        atomicAdd(&v_out[k4 * 4 + 3], acc.w);
    }
}

// ---- comb with fully-absorbed attention (unchanged) ----
__global__ void k_combattn(const float* __restrict__ wdot, const float* __restrict__ t,
                           const float* __restrict__ v, const float* __restrict__ hs,
                           const float* __restrict__ h2, const float* __restrict__ Wcomb,
                           const float* __restrict__ bcomb,
                           float* __restrict__ outv, float* __restrict__ outv2,
                           float* __restrict__ ato, float* __restrict__ pto) {
    const int u = blockIdx.x, tid = threadIdx.x;
    const int lane = tid & 63, wv = tid >> 6;
    __shared__ float red[4];
    __shared__ float ssc[32];
    __shared__ float sa[LL];
    float p;
    {
        const float4* w4 = (const float4*)wdot;
        const float4* t4 = (const float4*)t;
        float acc = dot4(w4[tid], t4[tid]);
        p = (float)LL * sigmoidf_(block_sum(acc, red));
    }
    if (u == 0 && tid == 0) pto[0] = p;
    const int si = (int)rintf(p);
    const int lo = max(si - 10, 0), hi = min(si + 10, LL - 1);
    const int W = hi - lo + 1;            // <= 21
    const float4* v4 = (const float4*)v;
    for (int l = lo + wv; l <= hi; l += 4) {
        const float4* row = (const float4*)(hs + (size_t)l * HH);
        float a = 0.f;
#pragma unroll
        for (int j = lane; j < 256; j += 64) a += dot4(row[j], v4[j]);
#pragma unroll
        for (int o = 32; o > 0; o >>= 1) a += __shfl_xor(a, o, 64);
        if (lane == 0) ssc[l - lo] = a;
    }
    __syncthreads();
    float M = -INFINITY;
    for (int i = 0; i < W; ++i) M = fmaxf(M, ssc[i]);
    float S = 0.f;
    for (int i = 0; i < W; ++i) S += expf(ssc[i] - M);
    {
        bool mask = (tid >= lo) && (tid <= hi);
        int wi = min(max(tid - lo, 0), 31);
        float e = mask ? expf(ssc[wi] - M) : 0.f;
        float d = (float)tid - p;
        float at = mask ? (e / S) * expf(d * d * 0.04f) : 0.f;  // exp(+d^2/(D/2)^2), faithful
        sa[tid] = at;
        if (u == 0) ato[tid] = at;
    }
    __syncthreads();
    const float4* hs4 = (const float4*)hs;
    float4 c = make_float4(0.f, 0.f, 0.f, 0.f);
    for (int l = lo; l <= hi; ++l) {
        float a = sa[l];
        float4 hv = hs4[(size_t)l * 256 + tid];
        c.x += a * hv.x; c.y += a * hv.y; c.z += a * hv.z; c.w += a * hv.w;
    }
    const float inv_win = 1.f / (float)W;
    c.x *= inv_win; c.y *= inv_win; c.z *= inv_win; c.w *= inv_win;
    {
        const float4* row = (const float4*)(Wcomb + (size_t)u * (2 * HH));
        const float4* h24 = (const float4*)h2;
        float acc = dot4(row[tid], c) + dot4(row[256 + tid], h24[tid]);
        float tot = block_sum(acc, red);
        if (tid == 0) {
            float h = tanhf(tot + bcomb[u]);
            outv[u] = h; outv2[u] = h;
        }
    }
}

// ---- logits (512 thr): wave w owns rows w, w+8192, ...; max-free exp-sum ----
__global__ __launch_bounds__(512) void k_logits(
    const float* __restrict__ Wout, const float* __restrict__ bout,
    const float* __restrict__ x, float* __restrict__ z,
    float* __restrict__ bsum) {
    const int tid = threadIdx.x, lane = tid & 63, wvi = tid >> 6;
    const int w = blockIdx.x * 8 + wvi;           // 0..8191
    const float4* x4 = (const float4*)x;
    float4 x0 = x4[lane], x1 = x4[lane + 64], x2 = x4[lane + 128], x3 = x4[lane + 192];
    float s = 0.f;
    for (int i = 0; i < MAXR; ++i) {
        int r = w + i * NWL;
        if (r < V) {
            const float4* row = (const float4*)(Wout + (size_t)r * 1024) + lane;
            float acc = dot4(row[0], x0) + dot4(row[64], x1)
                      + dot4(row[128], x2) + dot4(row[192], x3);
#pragma unroll
            for (int o = 32; o > 0; o >>= 1) acc += __shfl_xor(acc, o, 64);
            float zz = acc + bout[r];
            if (lane == 0) z[r] = zz;
            s += expf(zz);                // tanh-bounded x -> |z| small, no overflow
        }
    }
    __shared__ float wsv[8];
    if (lane == 0) wsv[wvi] = s;
    __syncthreads();
    if (tid == 0) {
        float S = 0.f;
#pragma unroll
        for (int q = 0; q < 8; ++q) S += wsv[q];
        bsum[blockIdx.x] = S;
    }
}

// ---- fused: sum 1024 block expsums -> logZ; y = z - logZ ----
__global__ void k_sub(const float* __restrict__ z, const float* __restrict__ bsum,
                      float* __restrict__ y) {
    const int tid = threadIdx.x;
    __shared__ float red[4];
    __shared__ float lzs;
    float s = 0.f;
    for (int i = tid; i < 1024; i += 256) s += bsum[i];
    float S = block_sum(s, red);
    if (tid == 0) lzs = logf(S);
    __syncthreads();
    const float lz = lzs;
    int i = blockIdx.x * 256 + tid;
    if (i < V) y[i] = z[i] - lz;
}

extern "C" void kernel_launch(void* const* d_in, const int* in_sizes, int n_in,
                              void* d_out, int out_size, void* d_ws, size_t ws_size,
                              hipStream_t stream) {
    const int*   tok   = (const int*)  d_in[0];
    const float* h0    = (const float*)d_in[1];
    const float* c0    = (const float*)d_in[2];
    const float* hs    = (const float*)d_in[3];
    const float* htt   = (const float*)d_in[4];
    const float* emb   = (const float*)d_in[5];
    const float* Wp    = (const float*)d_in[6];
    const float* wdot  = (const float*)d_in[7];
    const float* Wbil  = (const float*)d_in[8];
    const float* Wcomb = (const float*)d_in[9];
    const float* bcomb = (const float*)d_in[10];
    const float* Wih0  = (const float*)d_in[11];
    const float* Whh0  = (const float*)d_in[12];
    const float* bih0  = (const float*)d_in[13];
    const float* bhh0  = (const float*)d_in[14];
    const float* Wih1  = (const float*)d_in[15];
    const float* Whh1  = (const float*)d_in[16];
    const float* bih1  = (const float*)d_in[17];
    const float* bhh1  = (const float*)d_in[18];
    const float* Wout  = (const float*)d_in[19];
    const float* bout  = (const float*)d_in[20];

    float* out = (float*)d_out;
    float* ws  = (float*)d_ws;

    float* h1o  = out + O_H;
    float* h2o  = out + O_H + HH;
    float* c1o  = out + O_C;
    float* c2o  = out + O_C + HH;
    float* htto = out + O_HT;
    float* ato  = out + O_A;
    float* pto  = out + O_P;
    float* p1   = out;            // y[0..4096) as scratch; overwritten by k_sub

    hipLaunchKernelGGL(k_lstmA, dim3(1024), dim3(512), 0, stream,
                       Wih0, Whh0, Whh1, bih0, bhh0, emb, tok, htt, h0, c0,
                       h1o, c1o, ws + W_H1, p1, ws + W_V);
    hipLaunchKernelGGL(k_lstmB, dim3(1024), dim3(512), 0, stream,
                       Wih1, bih1, bhh1, ws + W_H1, p1, h0, c0,
                       h2o, c2o, ws + W_H2);
    hipLaunchKernelGGL(k_ptv, dim3(1024 + 32), dim3(256), 0, stream,
                       Wp, Wbil, ws + W_H2, ws + W_T, ws + W_V);
    hipLaunchKernelGGL(k_combattn, dim3(1024), dim3(256), 0, stream,
                       wdot, ws + W_T, ws + W_V, hs, ws + W_H2, Wcomb, bcomb,
                       htto, ws + W_H1, ato, pto);   // W_H1 reused as aligned x copy
    hipLaunchKernelGGL(k_logits, dim3(1024), dim3(512), 0, stream,
                       Wout, bout, ws + W_H1, ws + W_Z, ws + W_BS);
    hipLaunchKernelGGL(k_sub, dim3((V + 255) / 256), dim3(256), 0, stream,
                       ws + W_Z, ws + W_BS, out);
}